// Round 5
// baseline (176.058 us; speedup 1.0000x reference)
//
#include <hip/hip_runtime.h>
#include <hip/hip_bf16.h>
#include <cstdint>

// Problem dims (fixed by reference)
#define B_  16
#define N_  32
#define L_  2048
#define D_  16
#define M_  32
#define K_  3
#define W_  2046   // (L - K)/STRIDE + 1

typedef __bf16 bf16x8 __attribute__((ext_vector_type(8)));
typedef float  f32x4  __attribute__((ext_vector_type(4)));

union frag_cast { uint4 u; bf16x8 f; };

// pack two fp32 -> one u32 holding two RTNE bf16 (a in low half)
__device__ __forceinline__ uint32_t pk2(float a, float b) {
    __hip_bfloat162 p = __float22bfloat162_rn(make_float2(a, b));
    union { __hip_bfloat162 h; uint32_t u; } cv; cv.h = p; return cv.u;
}

// ---------------------------------------------------------------------------
// Setup: transpose + scale weights into MFMA B-fragment order in d_ws.
// (ROUND-3 VERIFIED MAPPING — do not touch.)
// GEMM: K index κ = (k*32 + n)*4 + x  (k-major), col c = m*4 + d.
// ws layout: uint4[ct(8)][kc(12)][lane(64)]; lane's uint4 = 8 bf16 =
// B[κ = kc*32 + (lane>>4)*8 + j][col = ct*16 + (lane&15)], j = 0..7.
// ---------------------------------------------------------------------------
__global__ __launch_bounds__(64) void caps_setup(const float* __restrict__ wp,
                                                 uint4* __restrict__ ws) {
    const int i    = blockIdx.x * 64 + threadIdx.x;   // 0..6143 (96 blocks)
    const int ct   = i / 768;
    const int rem  = i - ct * 768;
    const int kc   = rem >> 6;
    const int lane = rem & 63;
    const int q    = lane >> 4;
    const int col  = (ct << 4) | (lane & 15);
    const int m = col >> 2, d = col & 3;
    const int k  = kc >> 2;
    const int n0 = (kc & 3) * 8 + q * 2;
    float f[8];
#pragma unroll
    for (int j = 0; j < 8; ++j) {
        const int n = n0 + (j >> 2);
        const int x = j & 3;
        f[j] = wp[(((k * 32 + n) * 4 + x) * 4 + d) * 32 + m] * 0.03125f;
    }
    uint4 o;
    o.x = pk2(f[0], f[1]); o.y = pk2(f[2], f[3]);
    o.z = pk2(f[4], f[5]); o.w = pk2(f[6], f[7]);
    ws[i] = o;
}

// ---------------------------------------------------------------------------
// Main: block = 256 thr = 4 waves; wave owns 32 rows (8 w x 4 a) x 128 cols
// (2 row-tiles x 8 col-tiles).  Grid (64, 16) = 1024 blocks = 4 blocks/CU
// -> 16 waves/CU (launch_bounds(256,4) caps VGPR at 128; est use ~110).
// A frags straight from global fp32 (cvt in-reg); B frags from d_ws (L2).
// Everything below is Round-3's verified structure with rt-count 4 -> 2.
// ---------------------------------------------------------------------------
__global__ __launch_bounds__(256, 4) void caps_mfma(
    const float* __restrict__ xp,   // [B][N][L][16]
    const uint4* __restrict__ ws,   // B frags
    const float* __restrict__ gp,   // [16]
    const float* __restrict__ bp,   // [16]
    float* __restrict__ out)        // [B][M][W][16]
{
    const int tid   = threadIdx.x;
    const int wave  = tid >> 6;
    const int lane  = tid & 63;
    const int q     = lane >> 4;        // quad id
    const int l15   = lane & 15;
    const int dL    = lane & 3;         // d (out inner-of-4)
    const int msub  = (lane >> 2) & 3;  // m within col-tile
    const int b     = blockIdx.y;
    const int wbase = blockIdx.x * 32 + wave * 8;   // wave covers 8 w

    f32x4 acc[2][8];
#pragma unroll
    for (int rt = 0; rt < 2; ++rt)
#pragma unroll
        for (int ct = 0; ct < 8; ++ct)
            acc[rt][ct] = (f32x4){0.f, 0.f, 0.f, 0.f};

    // A row (lane&15) = w_sub*4 + a ; clamp padded w (loads stay in-bounds,
    // results masked at store)
    const float* baseA[2];
#pragma unroll
    for (int rt = 0; rt < 2; ++rt) {
        int wv = wbase + rt * 4 + (l15 >> 2);
        if (wv > W_ - 1) wv = W_ - 1;
        baseA[rt] = xp + ((size_t)(b * N_) * L_ + wv) * D_ + (l15 & 3) * 4;
    }

    for (int kc = 0; kc < 12; ++kc) {
        const int k    = kc >> 2;
        const int n0   = (kc & 3) * 8 + q * 2;
        const int off0 = (n0 * L_ + k) * D_;
        const int off1 = off0 + L_ * D_;

        bf16x8 afr[2];
#pragma unroll
        for (int rt = 0; rt < 2; ++rt) {
            const float4 f0 = *reinterpret_cast<const float4*>(baseA[rt] + off0);
            const float4 f1 = *reinterpret_cast<const float4*>(baseA[rt] + off1);
            frag_cast c;
            c.u.x = pk2(f0.x, f0.y); c.u.y = pk2(f0.z, f0.w);
            c.u.z = pk2(f1.x, f1.y); c.u.w = pk2(f1.z, f1.w);
            afr[rt] = c.f;
        }

        const uint4* wsRow = ws + kc * 64 + lane;
#pragma unroll
        for (int ct = 0; ct < 8; ++ct) {
            frag_cast c; c.u = wsRow[ct * 768];
#pragma unroll
            for (int rt = 0; rt < 2; ++rt)
                acc[rt][ct] = __builtin_amdgcn_mfma_f32_16x16x32_bf16(
                    afr[rt], c.f, acc[rt][ct], 0, 0, 0);
        }
    }

    // gamma/beta for this lane's 4 (a = reg r) slots
    float gmv[4], btv[4];
#pragma unroll
    for (int r = 0; r < 4; ++r) { gmv[r] = gp[r * 4 + dL]; btv[r] = bp[r * 4 + dL]; }

    // Fused LayerNorm + store. D layout: row = q*4 + r -> (w_sub=q, a=r);
    // col = l15 -> (m = ct*4+msub, d = dL). LN group (a,d) = 4 regs x 4 lanes.
#pragma unroll
    for (int rt = 0; rt < 2; ++rt) {
        const int wv = wbase + rt * 4 + q;
#pragma unroll
        for (int ct = 0; ct < 8; ++ct) {
            const f32x4 v = acc[rt][ct];
            float s  = v[0] + v[1] + v[2] + v[3];
            float sq = v[0]*v[0] + v[1]*v[1] + v[2]*v[2] + v[3]*v[3];
            s  += __shfl_xor(s, 1);  s  += __shfl_xor(s, 2);
            sq += __shfl_xor(sq, 1); sq += __shfl_xor(sq, 2);
            const float mu   = s * (1.f / 16.f);
            const float var  = sq * (1.f / 16.f) - mu * mu;
            const float rstd = rsqrtf(var + 1e-5f);
            if (wv < W_) {
                const int m = ct * 4 + msub;
                float* op = out + ((size_t)(b * M_ + m) * W_ + wv) * D_ + dL;
#pragma unroll
                for (int r = 0; r < 4; ++r)
                    op[r * 4] = gmv[r] * (v[r] - mu) * rstd + btv[r];
            }
        }
    }
}

extern "C" void kernel_launch(void* const* d_in, const int* in_sizes, int n_in,
                              void* d_out, int out_size, void* d_ws, size_t ws_size,
                              hipStream_t stream) {
    const float* x  = (const float*)d_in[0];
    const float* w  = (const float*)d_in[1];
    const float* g  = (const float*)d_in[2];
    const float* be = (const float*)d_in[3];
    float* out = (float*)d_out;

    caps_setup<<<96, 64, 0, stream>>>(w, (uint4*)d_ws);
    caps_mfma<<<dim3(64, 16), 256, 0, stream>>>(
        x, (const uint4*)d_ws, g, be, out);
}

// Round 6
// 142.053 us; speedup vs baseline: 1.2394x; 1.2394x over previous
//
#include <hip/hip_runtime.h>
#include <hip/hip_bf16.h>
#include <cstdint>

// Problem dims (fixed by reference)
#define B_  16
#define N_  32
#define L_  2048
#define D_  16
#define M_  32
#define K_  3
#define W_  2046   // (L - K)/STRIDE + 1

typedef __bf16 bf16x8 __attribute__((ext_vector_type(8)));
typedef float  f32x4  __attribute__((ext_vector_type(4)));

union frag_cast { uint4 u; bf16x8 f; };

// pack two fp32 -> one u32 holding two RTNE bf16 (a in low half)
__device__ __forceinline__ uint32_t pk2(float a, float b) {
    __hip_bfloat162 p = __float22bfloat162_rn(make_float2(a, b));
    union { __hip_bfloat162 h; uint32_t u; } cv; cv.h = p; return cv.u;
}

// ---------------------------------------------------------------------------
// Setup: transpose + scale weights into MFMA B-fragment order in d_ws.
// (ROUND-3/5 VERIFIED MAPPING — do not touch.)
// GEMM: K index κ = (k*32 + n)*4 + x  (k-major), col c = m*4 + d.
// ws layout: uint4[ct(8)][kc(12)][lane(64)]; lane's uint4 = 8 bf16 =
// B[κ = kc*32 + (lane>>4)*8 + j][col = ct*16 + (lane&15)], j = 0..7.
// ---------------------------------------------------------------------------
__global__ __launch_bounds__(64) void caps_setup(const float* __restrict__ wp,
                                                 uint4* __restrict__ ws) {
    const int i    = blockIdx.x * 64 + threadIdx.x;   // 0..6143 (96 blocks)
    const int ct   = i / 768;
    const int rem  = i - ct * 768;
    const int kc   = rem >> 6;
    const int lane = rem & 63;
    const int q    = lane >> 4;
    const int col  = (ct << 4) | (lane & 15);
    const int m = col >> 2, d = col & 3;
    const int k  = kc >> 2;
    const int n0 = (kc & 3) * 8 + q * 2;
    float f[8];
#pragma unroll
    for (int j = 0; j < 8; ++j) {
        const int n = n0 + (j >> 2);
        const int x = j & 3;
        f[j] = wp[(((k * 32 + n) * 4 + x) * 4 + d) * 32 + m] * 0.03125f;
    }
    uint4 o;
    o.x = pk2(f[0], f[1]); o.y = pk2(f[2], f[3]);
    o.z = pk2(f[4], f[5]); o.w = pk2(f[6], f[7]);
    ws[i] = o;
}

// x LDS tile layout: byte addr = (n>>1)*1184 + w_local*64 + (e>>2)*16 + (n&1)*8
// (+ (e&3)*2 within the 8B granule).  18 w rows x 32 n, bf16.  The 16-B granule
// at (n2, w, a) holds elems a*4..a*4+3 of n=2*n2 then of n=2*n2+1 — exactly one
// MFMA A-frag uint4 per lane, so the K-loop A-load is ONE ds_read_b128 whose
// offset (kn*4736 + k*64 + rt*256) is a compile-time immediate.
#define XSTRIDE_N2 1184
#define XLDS_BYTES (16 * XSTRIDE_N2)   // 18944 B

// ---------------------------------------------------------------------------
// Main: block = 256 thr = 4 waves; block covers 16 w x all 128 cols.
// Wave: 64 rows (16 w x 4 a) x 32 cols (2 col-tiles: ct = wave*2 + cp).
// B held in 48 VGPR (2 ct x 6 kc), reloaded at the K-loop midpoint.
// K-loop: pure LDS + MFMA, no barriers, no global loads.
// Grid (128, 16); launch_bounds(256,4) -> <=128 VGPR, 4 blocks/CU (50%).
// ---------------------------------------------------------------------------
__global__ __launch_bounds__(256, 4) void caps_mfma(
    const float* __restrict__ xp,   // [B][N][L][16]
    const uint4* __restrict__ ws,   // B frags
    const float* __restrict__ gp,   // [16]
    const float* __restrict__ bp,   // [16]
    float* __restrict__ out)        // [B][M][W][16]
{
    __shared__ __align__(16) unsigned char xs[XLDS_BYTES];

    const int tid  = threadIdx.x;
    const int wave = tid >> 6;
    const int lane = tid & 63;
    const int q    = lane >> 4;        // quad id
    const int l15  = lane & 15;
    const int dL   = lane & 3;         // d (out inner-of-4)
    const int msub = (lane >> 2) & 3;  // m within col-tile
    const int b    = blockIdx.y;
    const int Wb   = blockIdx.x * 16;  // block's first w

    // ---- stage x tile (18 w x 32 n) f32 -> bf16 LDS, coalesced ----
    const float* xb = xp + (size_t)b * N_ * L_ * D_;
#pragma unroll
    for (int i = 0; i < 9; ++i) {
        const int idx = i * 256 + tid;        // 0..2303 float4s
        const int f4  = idx & 3;
        const int wn  = idx >> 2;             // 0..575
        const int w   = wn % 18;
        const int n   = wn / 18;
        int gw = Wb + w; if (gw > L_ - 1) gw = L_ - 1;   // clamp halo
        const float4 f = *reinterpret_cast<const float4*>(
            xb + ((size_t)n * L_ + gw) * D_ + f4 * 4);
        uint2 v; v.x = pk2(f.x, f.y); v.y = pk2(f.z, f.w);
        *reinterpret_cast<uint2*>(
            &xs[(n >> 1) * XSTRIDE_N2 + w * 64 + f4 * 16 + (n & 1) * 8]) = v;
    }
    __syncthreads();

    f32x4 acc[4][2];
#pragma unroll
    for (int rt = 0; rt < 4; ++rt)
#pragma unroll
        for (int cp = 0; cp < 2; ++cp)
            acc[rt][cp] = (f32x4){0.f, 0.f, 0.f, 0.f};

    // Lane-dependent A base; everything kc/rt/k-dependent is an imm offset.
    const unsigned char* ap =
        &xs[q * XSTRIDE_N2 + (l15 >> 2) * 64 + (l15 & 3) * 16];
    const int ct0 = wave * 2;

#pragma unroll
    for (int h = 0; h < 2; ++h) {
        uint4 breg[2][6];
#pragma unroll
        for (int cp = 0; cp < 2; ++cp)
#pragma unroll
            for (int j = 0; j < 6; ++j)
                breg[cp][j] = ws[(ct0 + cp) * 768 + (h * 6 + j) * 64 + lane];
#pragma unroll
        for (int j = 0; j < 6; ++j) {
            const int kc = h * 6 + j;
            const int k  = kc >> 2;            // tap
            const int kn = kc & 3;             // n-chunk
            bf16x8 afr[4];
#pragma unroll
            for (int rt = 0; rt < 4; ++rt) {
                frag_cast c;
                c.u = *reinterpret_cast<const uint4*>(
                    ap + kn * 4736 + k * 64 + rt * 256);
                afr[rt] = c.f;
            }
#pragma unroll
            for (int cp = 0; cp < 2; ++cp) {
                frag_cast bc; bc.u = breg[cp][j];
#pragma unroll
                for (int rt = 0; rt < 4; ++rt)
                    acc[rt][cp] = __builtin_amdgcn_mfma_f32_16x16x32_bf16(
                        afr[rt], bc.f, acc[rt][cp], 0, 0, 0);
            }
        }
    }

    // gamma/beta for this lane's 4 (a = reg r) slots
    float gmv[4], btv[4];
#pragma unroll
    for (int r = 0; r < 4; ++r) { gmv[r] = gp[r * 4 + dL]; btv[r] = bp[r * 4 + dL]; }

    // Fused LayerNorm + store (R3/R5-VERIFIED). D layout: row = q*4 + r ->
    // (w_sub=q, a=r); col = l15 -> (m = ct*4+msub, d = dL).
#pragma unroll
    for (int rt = 0; rt < 4; ++rt) {
        const int wv = Wb + rt * 4 + q;
#pragma unroll
        for (int cp = 0; cp < 2; ++cp) {
            const f32x4 v = acc[rt][cp];
            float s  = v[0] + v[1] + v[2] + v[3];
            float sq = v[0]*v[0] + v[1]*v[1] + v[2]*v[2] + v[3]*v[3];
            s  += __shfl_xor(s, 1);  s  += __shfl_xor(s, 2);
            sq += __shfl_xor(sq, 1); sq += __shfl_xor(sq, 2);
            const float mu   = s * (1.f / 16.f);
            const float var  = sq * (1.f / 16.f) - mu * mu;
            const float rstd = rsqrtf(var + 1e-5f);
            if (wv < W_) {
                const int m = (ct0 + cp) * 4 + msub;
                float* op = out + ((size_t)(b * M_ + m) * W_ + wv) * D_ + dL;
#pragma unroll
                for (int r = 0; r < 4; ++r)
                    op[r * 4] = gmv[r] * (v[r] - mu) * rstd + btv[r];
            }
        }
    }
}

extern "C" void kernel_launch(void* const* d_in, const int* in_sizes, int n_in,
                              void* d_out, int out_size, void* d_ws, size_t ws_size,
                              hipStream_t stream) {
    const float* x  = (const float*)d_in[0];
    const float* w  = (const float*)d_in[1];
    const float* g  = (const float*)d_in[2];
    const float* be = (const float*)d_in[3];
    float* out = (float*)d_out;

    caps_setup<<<96, 64, 0, stream>>>(w, (uint4*)d_ws);
    caps_mfma<<<dim3(128, 16), 256, 0, stream>>>(
        x, (const uint4*)d_ws, g, be, out);
}